// Round 1
// baseline (2340.004 us; speedup 1.0000x reference)
//
#include <hip/hip_runtime.h>
#include <math.h>

#define T_DIM 300
#define J_DIM 25
#define CIN 64
#define COUT 128
#define B_DIM 64

// ---------------- scores kernel config ----------------
#define S_TS   3     // t per chunk
#define S_TSEG 30    // t per segment
#define S_NSEG 10    // segments over T
#define S_NCH  10    // chunks per segment
#define S_P    75    // positions per chunk = S_TS*25
#define S_PP   76    // padded row

// part[b][seg][i*625 + j1*25 + j2] — per-segment partial Gram matrices
__global__ __launch_bounds__(256) void scores_partial_kernel(
    const float* __restrict__ x,
    const float* __restrict__ Wa, const float* __restrict__ ba,
    const float* __restrict__ Wb, const float* __restrict__ bb,
    float* __restrict__ part)
{
    __shared__ float xs[64][S_PP];
    __shared__ float a1[32][S_PP];
    __shared__ float a2[32][S_PP];
    __shared__ float w1[32 * 64];
    __shared__ float w2[32 * 64];
    __shared__ float sc[3 * 625];

    const int tid = threadIdx.x;
    const int seg = blockIdx.x, b = blockIdx.y;

    for (int p = tid; p < 1875; p += 256) sc[p] = 0.0f;

    const float* xb = x + (size_t)b * (CIN * T_DIM * J_DIM);

    for (int ch = 0; ch < S_NCH; ++ch) {
        const int t0 = seg * S_TSEG + ch * S_TS;
        // stage x chunk: [64][75]
        for (int idx = tid; idx < 64 * S_P; idx += 256) {
            int c = idx / S_P, pos = idx - c * S_P;
            xs[c][pos] = xb[c * (T_DIM * J_DIM) + t0 * J_DIM + pos];
        }
        __syncthreads();
        for (int i = 0; i < 3; ++i) {
            // stage Wa_i, Wb_i
            for (int idx = tid; idx < 2048; idx += 256) {
                w1[idx] = Wa[i * 2048 + idx];
                w2[idx] = Wb[i * 2048 + idx];
            }
            __syncthreads();
            // embeddings a1 = Wa x + ba, a2 = Wb x + bb  (32 x 75 each)
            for (int idx = tid; idx < 2 * 32 * S_P; idx += 256) {
                int which = idx / (32 * S_P);
                int e = idx - which * (32 * S_P);
                int cp = e / S_P, pos = e - cp * S_P;
                const float* w = which ? &w2[cp * 64] : &w1[cp * 64];
                float s = which ? bb[i * 32 + cp] : ba[i * 32 + cp];
                #pragma unroll
                for (int c = 0; c < 64; ++c) s = fmaf(w[c], xs[c][pos], s);
                if (which) a2[cp][pos] = s; else a1[cp][pos] = s;
            }
            __syncthreads();
            // scores_i[j1][j2] += sum_{c',tl} a1[c'][tl*25+j1] * a2[c'][tl*25+j2]
            for (int p = tid; p < 625; p += 256) {
                int j1 = p / 25, j2 = p - j1 * 25;
                float s = 0.0f;
                #pragma unroll
                for (int k = 0; k < 32; ++k) {
                    #pragma unroll
                    for (int tl = 0; tl < S_TS; ++tl)
                        s = fmaf(a1[k][tl * 25 + j1], a2[k][tl * 25 + j2], s);
                }
                sc[i * 625 + p] += s;
            }
            __syncthreads();
        }
    }
    float* pg = part + ((size_t)b * S_NSEG + seg) * 1875;
    for (int p = tid; p < 1875; p += 256) pg[p] = sc[p];
}

// reduce partials, softmax over j1 per column j2, add PA + I -> G[b][i][j1][j2]
__global__ void softmax_kernel(const float* __restrict__ part,
                               const float* __restrict__ PA,
                               float* __restrict__ G)
{
    int bi = blockIdx.x;              // b*3 + i
    int b = bi / 3, i = bi - b * 3;
    int j2 = threadIdx.x;
    if (j2 >= 25) return;
    float v[25];
    float m = -1e30f;
    #pragma unroll
    for (int j1 = 0; j1 < 25; ++j1) {
        float s = 0.0f;
        for (int seg = 0; seg < S_NSEG; ++seg)
            s += part[((size_t)b * S_NSEG + seg) * 1875 + i * 625 + j1 * 25 + j2];
        v[j1] = s * (1.0f / 9600.0f);
        m = fmaxf(m, v[j1]);
    }
    float sum = 0.0f;
    #pragma unroll
    for (int j1 = 0; j1 < 25; ++j1) { v[j1] = expf(v[j1] - m); sum += v[j1]; }
    float r = 1.0f / sum;
    float* g = G + (size_t)bi * 625;
    #pragma unroll
    for (int j1 = 0; j1 < 25; ++j1)
        g[j1 * 25 + j2] = v[j1] * r + PA[(i * 25 + j1) * 25 + j2] + (j1 == j2 ? 1.0f : 0.0f);
}

// fold BN into weights: W'[o][k] (k<192: Wd_i*inv1, k>=192: Wdown*inv2), const[o]
__global__ void prep_kernel(
    const float* __restrict__ Wd, const float* __restrict__ bd,
    const float* __restrict__ Wdown, const float* __restrict__ bdown,
    const float* __restrict__ g1, const float* __restrict__ b1,
    const float* __restrict__ m1, const float* __restrict__ v1,
    const float* __restrict__ g2, const float* __restrict__ b2,
    const float* __restrict__ m2, const float* __restrict__ v2,
    float* __restrict__ Wp, float* __restrict__ cst)
{
    const int tid = threadIdx.x;
    for (int idx = tid; idx < COUT * 256; idx += 256) {
        int o = idx >> 8, k = idx & 255;
        float val;
        if (k < 192) {
            int i = k >> 6, c = k & 63;
            float inv = g1[o] * rsqrtf(v1[o] + 1e-5f);
            val = Wd[(i * COUT + o) * 64 + c] * inv;
        } else {
            float inv = g2[o] * rsqrtf(v2[o] + 1e-5f);
            val = Wdown[o * 64 + (k - 192)] * inv;
        }
        Wp[idx] = val;
    }
    if (tid < COUT) {
        int o = tid;
        float inv1 = g1[o] * rsqrtf(v1[o] + 1e-5f);
        float inv2 = g2[o] * rsqrtf(v2[o] + 1e-5f);
        cst[o] = (bd[o] + bd[COUT + o] + bd[2 * COUT + o]) * inv1
               + (b1[o] - m1[o] * inv1)
               + bdown[o] * inv2
               + (b2[o] - m2[o] * inv2);
    }
}

// ---------------- main fused kernel ----------------
#define M_TB  2      // t per chunk
#define M_P   50     // positions per chunk
#define M_NCH 150    // chunks over T

__global__ __launch_bounds__(512) void main_kernel(
    const float* __restrict__ x, const float* __restrict__ G,
    const float* __restrict__ Wp, const float* __restrict__ cst,
    float* __restrict__ out)
{
    __shared__ float xs[64][64];
    __shared__ float zb[64][64];
    __shared__ float gl[3 * 625];

    const int tid = threadIdx.x;
    const int chnk = blockIdx.x, b = blockIdx.y;
    const int t0 = chnk * M_TB;
    const int lane = tid & 63;
    const int og = __builtin_amdgcn_readfirstlane(tid >> 6);   // 0..7, wave-uniform

    const float* xb = x + (size_t)b * (CIN * T_DIM * J_DIM);

    for (int idx = tid; idx < 1875; idx += 512)
        gl[idx] = G[(size_t)b * 1875 + idx];
    for (int idx = tid; idx < 4096; idx += 512) {
        int c = idx >> 6, pos = idx & 63;
        xs[c][pos] = (pos < M_P) ? xb[c * (T_DIM * J_DIM) + t0 * J_DIM + pos] : 0.0f;
    }

    float acc[16];
    #pragma unroll
    for (int oi = 0; oi < 16; ++oi) acc[oi] = 0.0f;
    __syncthreads();

    for (int phase = 0; phase < 4; ++phase) {
        if (phase < 3) {
            // z_i[c][pos] = sum_j' xs[c][tl*25+j'] * G_i[j'][j]
            for (int idx = tid; idx < 4096; idx += 512) {
                int c = idx >> 6, pos = idx & 63;
                float s = 0.0f;
                if (pos < M_P) {
                    int tl = pos / 25, j = pos - tl * 25;
                    const float* gg = &gl[phase * 625 + j];
                    const float* xr = &xs[c][tl * 25];
                    #pragma unroll
                    for (int jp = 0; jp < 25; ++jp) s = fmaf(xr[jp], gg[jp * 25], s);
                }
                zb[c][pos] = s;
            }
        }
        __syncthreads();
        const float (*zs)[64] = (phase < 3) ? zb : xs;
        const float* wp = Wp + (og * 16) * 256 + phase * 64;  // uniform base -> s_load
        #pragma unroll 4
        for (int c = 0; c < 64; ++c) {
            float zv = zs[c][lane];
            #pragma unroll
            for (int oi = 0; oi < 16; ++oi)
                acc[oi] = fmaf(wp[oi * 256 + c], zv, acc[oi]);
        }
        __syncthreads();
    }

    if (lane < M_P) {
        float* ob = out + (size_t)b * (COUT * T_DIM * J_DIM) + (size_t)t0 * J_DIM + lane;
        #pragma unroll
        for (int oi = 0; oi < 16; ++oi) {
            int o = og * 16 + oi;
            ob[(size_t)o * (T_DIM * J_DIM)] = fmaxf(acc[oi] + cst[o], 0.0f);
        }
    }
}

extern "C" void kernel_launch(void* const* d_in, const int* in_sizes, int n_in,
                              void* d_out, int out_size, void* d_ws, size_t ws_size,
                              hipStream_t stream)
{
    const float* x     = (const float*)d_in[0];
    const float* PA    = (const float*)d_in[1];
    const float* Wa    = (const float*)d_in[2];
    const float* ba    = (const float*)d_in[3];
    const float* Wb    = (const float*)d_in[4];
    const float* bb    = (const float*)d_in[5];
    const float* Wd    = (const float*)d_in[6];
    const float* bd    = (const float*)d_in[7];
    const float* Wdown = (const float*)d_in[8];
    const float* bdown = (const float*)d_in[9];
    const float* bn_g  = (const float*)d_in[10];
    const float* bn_b  = (const float*)d_in[11];
    const float* bn_m  = (const float*)d_in[12];
    const float* bn_v  = (const float*)d_in[13];
    const float* dn_g  = (const float*)d_in[14];
    const float* dn_b  = (const float*)d_in[15];
    const float* dn_m  = (const float*)d_in[16];
    const float* dn_v  = (const float*)d_in[17];

    float* ws   = (float*)d_ws;
    float* part = ws;                    // 64*10*1875 = 1,200,000 floats
    float* G    = ws + 1200000;          // 120,000
    float* Wp   = ws + 1320000;          // 32,768
    float* cst  = ws + 1352768;          // 128

    prep_kernel<<<1, 256, 0, stream>>>(Wd, bd, Wdown, bdown,
        bn_g, bn_b, bn_m, bn_v, dn_g, dn_b, dn_m, dn_v, Wp, cst);
    scores_partial_kernel<<<dim3(S_NSEG, B_DIM), 256, 0, stream>>>(x, Wa, ba, Wb, bb, part);
    softmax_kernel<<<dim3(B_DIM * 3), 64, 0, stream>>>(part, PA, G);
    main_kernel<<<dim3(M_NCH, B_DIM), 512, 0, stream>>>(x, G, Wp, cst, (float*)d_out);
}

// Round 2
// 1400.977 us; speedup vs baseline: 1.6703x; 1.6703x over previous
//
#include <hip/hip_runtime.h>
#include <math.h>

#define T_DIM 300
#define J_DIM 25
#define CIN 64
#define COUT 128
#define B_DIM 64

// ---------------- scores kernel config ----------------
#define SC_TC   20    // t per chunk
#define SC_CP   500   // positions per chunk = SC_TC*25
#define SC_NCH  5     // chunks per segment
#define SC_NSEG 3     // segments over T (each 100 t)

// part[((b*3+i)*SC_NSEG+seg)*625 + j1*25 + j2]
__global__ __launch_bounds__(512) void scores_kernel(
    const float* __restrict__ x,
    const float* __restrict__ Wa, const float* __restrict__ ba,
    const float* __restrict__ Wb, const float* __restrict__ bb,
    float* __restrict__ part)
{
    __shared__ float w1T[64][32];
    __shared__ float w2T[64][32];
    __shared__ float a1[32][SC_CP];
    __shared__ float a2[32][SC_CP];

    const int tid = threadIdx.x;
    const int ig  = blockIdx.x / SC_NSEG;   // subset i
    const int seg = blockIdx.x % SC_NSEG;
    const int b   = blockIdx.y;
    const int lane = tid & 63;
    const int wv   = __builtin_amdgcn_readfirstlane(tid >> 6);  // 0..7
    const int kb   = wv * 4;                // wave's 4 k-channels

    // stage transposed weights once
    for (int idx = tid; idx < 2048; idx += 512) {
        int c = idx >> 5, k = idx & 31;
        w1T[c][k] = Wa[ig * 2048 + k * 64 + c];
        w2T[c][k] = Wb[ig * 2048 + k * 64 + c];
    }

    // gram accumulators (registers, persist across chunks)
    float g0 = 0.0f, g1 = 0.0f;
    const int o0 = tid;                       // output j1*25+j2 = o0
    const int j1a = o0 / 25, j2a = o0 - (o0 / 25) * 25;
    const int o1 = tid + 512;                 // second output, valid if tid<113
    const int j1b = o1 / 25, j2b = o1 - (o1 / 25) * 25;

    const float bav0 = ba[ig * 32 + kb + 0], bav1 = ba[ig * 32 + kb + 1];
    const float bav2 = ba[ig * 32 + kb + 2], bav3 = ba[ig * 32 + kb + 3];
    const float bbv0 = bb[ig * 32 + kb + 0], bbv1 = bb[ig * 32 + kb + 1];
    const float bbv2 = bb[ig * 32 + kb + 2], bbv3 = bb[ig * 32 + kb + 3];

    __syncthreads();

    const float* xb = x + (size_t)b * (CIN * T_DIM * J_DIM);
    const int s0 = lane * 4;
    const int s1 = 256 + lane * 4;                         // may exceed 499
    const int s1ld = (s1 <= SC_CP - 4) ? s1 : (SC_CP - 4); // clamped load addr
    const bool s1ok = (s1 <= SC_CP - 4);

    for (int ch = 0; ch < SC_NCH; ++ch) {
        const int pb = seg * (SC_NCH * SC_CP) + ch * SC_CP;

        // ---- embedding: a1 = Wa*x + ba, a2 = Wb*x + bb for this chunk ----
        float acc1[4][8], acc2[4][8];
        #pragma unroll
        for (int p = 0; p < 8; ++p) {
            acc1[0][p] = bav0; acc1[1][p] = bav1; acc1[2][p] = bav2; acc1[3][p] = bav3;
            acc2[0][p] = bbv0; acc2[1][p] = bbv1; acc2[2][p] = bbv2; acc2[3][p] = bbv3;
        }
        #pragma unroll 4
        for (int c = 0; c < 64; ++c) {
            const float4 xv0 = *(const float4*)&xb[c * 7500 + pb + s0];
            const float4 xv1 = *(const float4*)&xb[c * 7500 + pb + s1ld];
            const float4 wq1 = *(const float4*)&w1T[c][kb];
            const float4 wq2 = *(const float4*)&w2T[c][kb];
            #pragma unroll
            for (int q = 0; q < 4; ++q) {
                const float w1v = ((const float*)&wq1)[q];
                const float w2v = ((const float*)&wq2)[q];
                acc1[q][0] = fmaf(w1v, xv0.x, acc1[q][0]);
                acc1[q][1] = fmaf(w1v, xv0.y, acc1[q][1]);
                acc1[q][2] = fmaf(w1v, xv0.z, acc1[q][2]);
                acc1[q][3] = fmaf(w1v, xv0.w, acc1[q][3]);
                acc1[q][4] = fmaf(w1v, xv1.x, acc1[q][4]);
                acc1[q][5] = fmaf(w1v, xv1.y, acc1[q][5]);
                acc1[q][6] = fmaf(w1v, xv1.z, acc1[q][6]);
                acc1[q][7] = fmaf(w1v, xv1.w, acc1[q][7]);
                acc2[q][0] = fmaf(w2v, xv0.x, acc2[q][0]);
                acc2[q][1] = fmaf(w2v, xv0.y, acc2[q][1]);
                acc2[q][2] = fmaf(w2v, xv0.z, acc2[q][2]);
                acc2[q][3] = fmaf(w2v, xv0.w, acc2[q][3]);
                acc2[q][4] = fmaf(w2v, xv1.x, acc2[q][4]);
                acc2[q][5] = fmaf(w2v, xv1.y, acc2[q][5]);
                acc2[q][6] = fmaf(w2v, xv1.z, acc2[q][6]);
                acc2[q][7] = fmaf(w2v, xv1.w, acc2[q][7]);
            }
        }
        #pragma unroll
        for (int q = 0; q < 4; ++q) {
            *(float4*)&a1[kb + q][s0] = make_float4(acc1[q][0], acc1[q][1], acc1[q][2], acc1[q][3]);
            *(float4*)&a2[kb + q][s0] = make_float4(acc2[q][0], acc2[q][1], acc2[q][2], acc2[q][3]);
            if (s1ok) {
                *(float4*)&a1[kb + q][s1] = make_float4(acc1[q][4], acc1[q][5], acc1[q][6], acc1[q][7]);
                *(float4*)&a2[kb + q][s1] = make_float4(acc2[q][4], acc2[q][5], acc2[q][6], acc2[q][7]);
            }
        }
        __syncthreads();

        // ---- gram accumulate: g[j1][j2] += sum_{k,t} a1[k][t*25+j1]*a2[k][t*25+j2] ----
        for (int k = 0; k < 32; ++k) {
            const float* r1 = &a1[k][0];
            const float* r2 = &a2[k][0];
            #pragma unroll 4
            for (int t = 0; t < SC_TC; ++t)
                g0 = fmaf(r1[t * 25 + j1a], r2[t * 25 + j2a], g0);
        }
        if (tid < 113) {
            for (int k = 0; k < 32; ++k) {
                const float* r1 = &a1[k][0];
                const float* r2 = &a2[k][0];
                #pragma unroll 4
                for (int t = 0; t < SC_TC; ++t)
                    g1 = fmaf(r1[t * 25 + j1b], r2[t * 25 + j2b], g1);
            }
        }
        __syncthreads();
    }

    float* pg = part + ((size_t)(b * 3 + ig) * SC_NSEG + seg) * 625;
    pg[o0] = g0;
    if (tid < 113) pg[o1] = g1;
}

// reduce partials, softmax over j1 per column j2, add PA + I -> G[b][i][j1][j2]
__global__ void softmax_kernel(const float* __restrict__ part,
                               const float* __restrict__ PA,
                               float* __restrict__ G)
{
    int bi = blockIdx.x;              // b*3 + i
    int b = bi / 3, i = bi - b * 3;
    int j2 = threadIdx.x;
    if (j2 >= 25) return;
    float v[25];
    float m = -1e30f;
    #pragma unroll
    for (int j1 = 0; j1 < 25; ++j1) {
        float s = 0.0f;
        for (int seg = 0; seg < SC_NSEG; ++seg)
            s += part[((size_t)bi * SC_NSEG + seg) * 625 + j1 * 25 + j2];
        v[j1] = s * (1.0f / 9600.0f);
        m = fmaxf(m, v[j1]);
    }
    float sum = 0.0f;
    #pragma unroll
    for (int j1 = 0; j1 < 25; ++j1) { v[j1] = expf(v[j1] - m); sum += v[j1]; }
    float r = 1.0f / sum;
    float* g = G + (size_t)bi * 625;
    #pragma unroll
    for (int j1 = 0; j1 < 25; ++j1)
        g[j1 * 25 + j2] = v[j1] * r + PA[(i * 25 + j1) * 25 + j2] + (j1 == j2 ? 1.0f : 0.0f);
}

// fold BN into weights: W'[o][k] (k<192: Wd_i*inv1, k>=192: Wdown*inv2), const[o]
__global__ void prep_kernel(
    const float* __restrict__ Wd, const float* __restrict__ bd,
    const float* __restrict__ Wdown, const float* __restrict__ bdown,
    const float* __restrict__ g1, const float* __restrict__ b1,
    const float* __restrict__ m1, const float* __restrict__ v1,
    const float* __restrict__ g2, const float* __restrict__ b2,
    const float* __restrict__ m2, const float* __restrict__ v2,
    float* __restrict__ Wp, float* __restrict__ cst)
{
    const int tid = threadIdx.x;
    for (int idx = tid; idx < COUT * 256; idx += 256) {
        int o = idx >> 8, k = idx & 255;
        float val;
        if (k < 192) {
            int i = k >> 6, c = k & 63;
            float inv = g1[o] * rsqrtf(v1[o] + 1e-5f);
            val = Wd[(i * COUT + o) * 64 + c] * inv;
        } else {
            float inv = g2[o] * rsqrtf(v2[o] + 1e-5f);
            val = Wdown[o * 64 + (k - 192)] * inv;
        }
        Wp[idx] = val;
    }
    if (tid < COUT) {
        int o = tid;
        float inv1 = g1[o] * rsqrtf(v1[o] + 1e-5f);
        float inv2 = g2[o] * rsqrtf(v2[o] + 1e-5f);
        cst[o] = (bd[o] + bd[COUT + o] + bd[2 * COUT + o]) * inv1
               + (b1[o] - m1[o] * inv1)
               + bdown[o] * inv2
               + (b2[o] - m2[o] * inv2);
    }
}

// ---------------- main fused kernel ----------------
#define M_TB  2      // t per chunk
#define M_P   50     // positions per chunk
#define M_NCH 150    // chunks over T

__global__ __launch_bounds__(512) void main_kernel(
    const float* __restrict__ x, const float* __restrict__ G,
    const float* __restrict__ Wp, const float* __restrict__ cst,
    float* __restrict__ out)
{
    __shared__ float xs[64][64];
    __shared__ float zb[64][64];
    __shared__ float gl[3 * 625];

    const int tid = threadIdx.x;
    const int chnk = blockIdx.x, b = blockIdx.y;
    const int t0 = chnk * M_TB;
    const int lane = tid & 63;
    const int og = __builtin_amdgcn_readfirstlane(tid >> 6);   // 0..7, wave-uniform

    const float* xb = x + (size_t)b * (CIN * T_DIM * J_DIM);

    for (int idx = tid; idx < 1875; idx += 512)
        gl[idx] = G[(size_t)b * 1875 + idx];
    for (int idx = tid; idx < 4096; idx += 512) {
        int c = idx >> 6, pos = idx & 63;
        xs[c][pos] = (pos < M_P) ? xb[c * (T_DIM * J_DIM) + t0 * J_DIM + pos] : 0.0f;
    }

    float acc[16];
    #pragma unroll
    for (int oi = 0; oi < 16; ++oi) acc[oi] = 0.0f;
    __syncthreads();

    for (int phase = 0; phase < 4; ++phase) {
        if (phase < 3) {
            // z_i[c][pos] = sum_j' xs[c][tl*25+j'] * G_i[j'][j]
            for (int idx = tid; idx < 4096; idx += 512) {
                int c = idx >> 6, pos = idx & 63;
                float s = 0.0f;
                if (pos < M_P) {
                    int tl = pos / 25, j = pos - tl * 25;
                    const float* gg = &gl[phase * 625 + j];
                    const float* xr = &xs[c][tl * 25];
                    #pragma unroll
                    for (int jp = 0; jp < 25; ++jp) s = fmaf(xr[jp], gg[jp * 25], s);
                }
                zb[c][pos] = s;
            }
        }
        __syncthreads();
        const float (*zs)[64] = (phase < 3) ? zb : xs;
        const float* wp = Wp + (og * 16) * 256 + phase * 64;  // uniform base -> s_load
        #pragma unroll 4
        for (int c = 0; c < 64; ++c) {
            float zv = zs[c][lane];
            #pragma unroll
            for (int oi = 0; oi < 16; ++oi)
                acc[oi] = fmaf(wp[oi * 256 + c], zv, acc[oi]);
        }
        __syncthreads();
    }

    if (lane < M_P) {
        float* ob = out + (size_t)b * (COUT * T_DIM * J_DIM) + (size_t)t0 * J_DIM + lane;
        #pragma unroll
        for (int oi = 0; oi < 16; ++oi) {
            int o = og * 16 + oi;
            ob[(size_t)o * (T_DIM * J_DIM)] = fmaxf(acc[oi] + cst[o], 0.0f);
        }
    }
}

extern "C" void kernel_launch(void* const* d_in, const int* in_sizes, int n_in,
                              void* d_out, int out_size, void* d_ws, size_t ws_size,
                              hipStream_t stream)
{
    const float* x     = (const float*)d_in[0];
    const float* PA    = (const float*)d_in[1];
    const float* Wa    = (const float*)d_in[2];
    const float* ba    = (const float*)d_in[3];
    const float* Wb    = (const float*)d_in[4];
    const float* bb    = (const float*)d_in[5];
    const float* Wd    = (const float*)d_in[6];
    const float* bd    = (const float*)d_in[7];
    const float* Wdown = (const float*)d_in[8];
    const float* bdown = (const float*)d_in[9];
    const float* bn_g  = (const float*)d_in[10];
    const float* bn_b  = (const float*)d_in[11];
    const float* bn_m  = (const float*)d_in[12];
    const float* bn_v  = (const float*)d_in[13];
    const float* dn_g  = (const float*)d_in[14];
    const float* dn_b  = (const float*)d_in[15];
    const float* dn_m  = (const float*)d_in[16];
    const float* dn_v  = (const float*)d_in[17];

    float* ws   = (float*)d_ws;
    float* part = ws;                    // 64*3*3*625 = 360,000 floats
    float* G    = ws + 360000;           // 120,000
    float* Wp   = ws + 480000;           // 32,768
    float* cst  = ws + 512768;           // 128

    prep_kernel<<<1, 256, 0, stream>>>(Wd, bd, Wdown, bdown,
        bn_g, bn_b, bn_m, bn_v, dn_g, dn_b, dn_m, dn_v, Wp, cst);
    scores_kernel<<<dim3(3 * SC_NSEG, B_DIM), 512, 0, stream>>>(x, Wa, ba, Wb, bb, part);
    softmax_kernel<<<dim3(B_DIM * 3), 64, 0, stream>>>(part, PA, G);
    main_kernel<<<dim3(M_NCH, B_DIM), 512, 0, stream>>>(x, G, Wp, cst, (float*)d_out);
}

// Round 3
// 898.800 us; speedup vs baseline: 2.6035x; 1.5587x over previous
//
#include <hip/hip_runtime.h>
#include <math.h>

#define T_DIM 300
#define J_DIM 25
#define CIN 64
#define COUT 128
#define B_DIM 64

typedef __attribute__((ext_vector_type(8))) short bf16x8;
typedef __attribute__((ext_vector_type(4))) float f32x4;

__device__ __forceinline__ unsigned short f2bf(float f) {
    union { float f; unsigned u; } v; v.f = f;
    unsigned r = v.u + 0x7FFF + ((v.u >> 16) & 1);   // RNE
    return (unsigned short)(r >> 16);
}

// ---------------- scores kernel (unchanged from R1, passed) ----------------
#define SC_TC   20
#define SC_CP   500
#define SC_NCH  5
#define SC_NSEG 3

__global__ __launch_bounds__(512) void scores_kernel(
    const float* __restrict__ x,
    const float* __restrict__ Wa, const float* __restrict__ ba,
    const float* __restrict__ Wb, const float* __restrict__ bb,
    float* __restrict__ part)
{
    __shared__ float w1T[64][32];
    __shared__ float w2T[64][32];
    __shared__ float a1[32][SC_CP];
    __shared__ float a2[32][SC_CP];

    const int tid = threadIdx.x;
    const int ig  = blockIdx.x / SC_NSEG;
    const int seg = blockIdx.x % SC_NSEG;
    const int b   = blockIdx.y;
    const int lane = tid & 63;
    const int wv   = __builtin_amdgcn_readfirstlane(tid >> 6);
    const int kb   = wv * 4;

    for (int idx = tid; idx < 2048; idx += 512) {
        int c = idx >> 5, k = idx & 31;
        w1T[c][k] = Wa[ig * 2048 + k * 64 + c];
        w2T[c][k] = Wb[ig * 2048 + k * 64 + c];
    }

    float g0 = 0.0f, g1 = 0.0f;
    const int o0 = tid;
    const int j1a = o0 / 25, j2a = o0 - (o0 / 25) * 25;
    const int o1 = tid + 512;
    const int j1b = o1 / 25, j2b = o1 - (o1 / 25) * 25;

    const float bav0 = ba[ig * 32 + kb + 0], bav1 = ba[ig * 32 + kb + 1];
    const float bav2 = ba[ig * 32 + kb + 2], bav3 = ba[ig * 32 + kb + 3];
    const float bbv0 = bb[ig * 32 + kb + 0], bbv1 = bb[ig * 32 + kb + 1];
    const float bbv2 = bb[ig * 32 + kb + 2], bbv3 = bb[ig * 32 + kb + 3];

    __syncthreads();

    const float* xb = x + (size_t)b * (CIN * T_DIM * J_DIM);
    const int s0 = lane * 4;
    const int s1 = 256 + lane * 4;
    const int s1ld = (s1 <= SC_CP - 4) ? s1 : (SC_CP - 4);
    const bool s1ok = (s1 <= SC_CP - 4);

    for (int ch = 0; ch < SC_NCH; ++ch) {
        const int pb = seg * (SC_NCH * SC_CP) + ch * SC_CP;

        float acc1[4][8], acc2[4][8];
        #pragma unroll
        for (int p = 0; p < 8; ++p) {
            acc1[0][p] = bav0; acc1[1][p] = bav1; acc1[2][p] = bav2; acc1[3][p] = bav3;
            acc2[0][p] = bbv0; acc2[1][p] = bbv1; acc2[2][p] = bbv2; acc2[3][p] = bbv3;
        }
        #pragma unroll 4
        for (int c = 0; c < 64; ++c) {
            const float4 xv0 = *(const float4*)&xb[c * 7500 + pb + s0];
            const float4 xv1 = *(const float4*)&xb[c * 7500 + pb + s1ld];
            const float4 wq1 = *(const float4*)&w1T[c][kb];
            const float4 wq2 = *(const float4*)&w2T[c][kb];
            #pragma unroll
            for (int q = 0; q < 4; ++q) {
                const float w1v = ((const float*)&wq1)[q];
                const float w2v = ((const float*)&wq2)[q];
                acc1[q][0] = fmaf(w1v, xv0.x, acc1[q][0]);
                acc1[q][1] = fmaf(w1v, xv0.y, acc1[q][1]);
                acc1[q][2] = fmaf(w1v, xv0.z, acc1[q][2]);
                acc1[q][3] = fmaf(w1v, xv0.w, acc1[q][3]);
                acc1[q][4] = fmaf(w1v, xv1.x, acc1[q][4]);
                acc1[q][5] = fmaf(w1v, xv1.y, acc1[q][5]);
                acc1[q][6] = fmaf(w1v, xv1.z, acc1[q][6]);
                acc1[q][7] = fmaf(w1v, xv1.w, acc1[q][7]);
                acc2[q][0] = fmaf(w2v, xv0.x, acc2[q][0]);
                acc2[q][1] = fmaf(w2v, xv0.y, acc2[q][1]);
                acc2[q][2] = fmaf(w2v, xv0.z, acc2[q][2]);
                acc2[q][3] = fmaf(w2v, xv0.w, acc2[q][3]);
                acc2[q][4] = fmaf(w2v, xv1.x, acc2[q][4]);
                acc2[q][5] = fmaf(w2v, xv1.y, acc2[q][5]);
                acc2[q][6] = fmaf(w2v, xv1.z, acc2[q][6]);
                acc2[q][7] = fmaf(w2v, xv1.w, acc2[q][7]);
            }
        }
        #pragma unroll
        for (int q = 0; q < 4; ++q) {
            *(float4*)&a1[kb + q][s0] = make_float4(acc1[q][0], acc1[q][1], acc1[q][2], acc1[q][3]);
            *(float4*)&a2[kb + q][s0] = make_float4(acc2[q][0], acc2[q][1], acc2[q][2], acc2[q][3]);
            if (s1ok) {
                *(float4*)&a1[kb + q][s1] = make_float4(acc1[q][4], acc1[q][5], acc1[q][6], acc1[q][7]);
                *(float4*)&a2[kb + q][s1] = make_float4(acc2[q][4], acc2[q][5], acc2[q][6], acc2[q][7]);
            }
        }
        __syncthreads();

        for (int k = 0; k < 32; ++k) {
            const float* r1 = &a1[k][0];
            const float* r2 = &a2[k][0];
            #pragma unroll 4
            for (int t = 0; t < SC_TC; ++t)
                g0 = fmaf(r1[t * 25 + j1a], r2[t * 25 + j2a], g0);
        }
        if (tid < 113) {
            for (int k = 0; k < 32; ++k) {
                const float* r1 = &a1[k][0];
                const float* r2 = &a2[k][0];
                #pragma unroll 4
                for (int t = 0; t < SC_TC; ++t)
                    g1 = fmaf(r1[t * 25 + j1b], r2[t * 25 + j2b], g1);
            }
        }
        __syncthreads();
    }

    float* pg = part + ((size_t)(b * 3 + ig) * SC_NSEG + seg) * 625;
    pg[o0] = g0;
    if (tid < 113) pg[o1] = g1;
}

// ---------------- softmax (unchanged) ----------------
__global__ void softmax_kernel(const float* __restrict__ part,
                               const float* __restrict__ PA,
                               float* __restrict__ G)
{
    int bi = blockIdx.x;
    int b = bi / 3, i = bi - b * 3;
    int j2 = threadIdx.x;
    if (j2 >= 25) return;
    float v[25];
    float m = -1e30f;
    #pragma unroll
    for (int j1 = 0; j1 < 25; ++j1) {
        float s = 0.0f;
        for (int seg = 0; seg < SC_NSEG; ++seg)
            s += part[((size_t)bi * SC_NSEG + seg) * 625 + j1 * 25 + j2];
        v[j1] = s * (1.0f / 9600.0f);
        m = fmaxf(m, v[j1]);
    }
    float sum = 0.0f;
    #pragma unroll
    for (int j1 = 0; j1 < 25; ++j1) { v[j1] = expf(v[j1] - m); sum += v[j1]; }
    float r = 1.0f / sum;
    float* g = G + (size_t)bi * 625;
    #pragma unroll
    for (int j1 = 0; j1 < 25; ++j1)
        g[j1 * 25 + j2] = v[j1] * r + PA[(i * 25 + j1) * 25 + j2] + (j1 == j2 ? 1.0f : 0.0f);
}

// ---------------- prep: fold BN, emit W' in bf16 [128][256] + cst ----------------
__global__ void prep_kernel(
    const float* __restrict__ Wd, const float* __restrict__ bd,
    const float* __restrict__ Wdown, const float* __restrict__ bdown,
    const float* __restrict__ g1, const float* __restrict__ b1,
    const float* __restrict__ m1, const float* __restrict__ v1,
    const float* __restrict__ g2, const float* __restrict__ b2,
    const float* __restrict__ m2, const float* __restrict__ v2,
    unsigned short* __restrict__ Wpb, float* __restrict__ cst)
{
    const int tid = threadIdx.x;
    for (int idx = tid; idx < COUT * 256; idx += 256) {
        int o = idx >> 8, k = idx & 255;
        float val;
        if (k < 192) {
            int i = k >> 6, c = k & 63;
            float inv = g1[o] * rsqrtf(v1[o] + 1e-5f);
            val = Wd[(i * COUT + o) * 64 + c] * inv;
        } else {
            float inv = g2[o] * rsqrtf(v2[o] + 1e-5f);
            val = Wdown[o * 64 + (k - 192)] * inv;
        }
        Wpb[idx] = f2bf(val);
    }
    if (tid < COUT) {
        int o = tid;
        float inv1 = g1[o] * rsqrtf(v1[o] + 1e-5f);
        float inv2 = g2[o] * rsqrtf(v2[o] + 1e-5f);
        cst[o] = (bd[o] + bd[COUT + o] + bd[2 * COUT + o]) * inv1
               + (b1[o] - m1[o] * inv1)
               + bdown[o] * inv2
               + (b2[o] - m2[o] * inv2);
    }
}

// ---------------- main fused kernel: VALU z + MFMA GEMM ----------------
// block = (b, 4 t rows) = 100 positions; K=256 split into 2 halves of 128.
__global__ __launch_bounds__(512, 4) void main_kernel(
    const float* __restrict__ x, const float* __restrict__ G,
    const unsigned short* __restrict__ Wpb, const float* __restrict__ cst,
    float* __restrict__ out)
{
    __shared__ float xs[64][104];     // x window, fp32 (pos = t*25+j, 100 valid)
    __shared__ uint4 zxs[16][113];    // half-K B tile: [kgrp(8k)][pos] 16B units
    __shared__ float gl[1875];        // G for this b, fp32

    const int tid  = threadIdx.x;
    const int b    = blockIdx.y;
    const int t0   = blockIdx.x * 4;
    const int lane = tid & 63;
    const int w    = __builtin_amdgcn_readfirstlane(tid >> 6);  // wave 0..7
    const int g4   = lane >> 4;       // 0..3
    const int c16  = lane & 15;       // 0..15

    const float* xb = x + (size_t)b * (CIN * T_DIM * J_DIM) + t0 * 25;

    // A-fragments: wave w owns output rows [16w,16w+16); 8 k-steps of 32
    bf16x8 afr[8];
    {
        const unsigned short* wrow = Wpb + (w * 16 + c16) * 256 + g4 * 8;
        #pragma unroll
        for (int f = 0; f < 8; ++f)
            afr[f] = *reinterpret_cast<const bf16x8*>(wrow + f * 32);
    }

    // stage x window (64 rows x 100 floats, float4 loads)
    for (int idx = tid; idx < 64 * 25; idx += 512) {
        int c = idx / 25, q = idx - c * 25;
        *(float4*)&xs[c][q * 4] = *(const float4*)(xb + c * 7500 + q * 4);
    }
    // stage G
    for (int idx = tid; idx < 1875; idx += 512)
        gl[idx] = G[(size_t)b * 1875 + idx];

    // z-thread mapping
    const int pg   = tid >> 7;        // 0..3 -> c range [pg*16, pg*16+16)
    const int posn = tid & 127;       // valid if < 100
    const int tl   = posn / 25;
    const int jl   = posn - tl * 25;
    const bool zact = (posn < 100);

    f32x4 acc[7];
    #pragma unroll
    for (int n = 0; n < 7; ++n) acc[n] = (f32x4){0.f, 0.f, 0.f, 0.f};

    __syncthreads();

    for (int h = 0; h < 2; ++h) {
        // ---- produce zxs for this K-half (k = h*128 .. h*128+128) ----
        #pragma unroll
        for (int p = 0; p < 2; ++p) {
            const int slot = 2 * h + p;            // 0..2: z_i, 3: x
            if (zact) {
                float za[16];
                if (slot < 3) {
                    #pragma unroll
                    for (int i = 0; i < 16; ++i) za[i] = 0.0f;
                    const float* gcol = gl + slot * 625 + jl;
                    const int xo = tl * 25;
                    for (int jp = 0; jp < 25; ++jp) {
                        const float gv = gcol[jp * 25];
                        #pragma unroll
                        for (int i = 0; i < 16; ++i)
                            za[i] = fmaf(xs[pg * 16 + i][xo + jp], gv, za[i]);
                    }
                } else {
                    #pragma unroll
                    for (int i = 0; i < 16; ++i) za[i] = xs[pg * 16 + i][posn];
                }
                unsigned d[8];
                #pragma unroll
                for (int m = 0; m < 8; ++m)
                    d[m] = (unsigned)f2bf(za[2 * m]) | ((unsigned)f2bf(za[2 * m + 1]) << 16);
                const int kg = p * 8 + pg * 2;
                zxs[kg][posn]     = make_uint4(d[0], d[1], d[2], d[3]);
                zxs[kg + 1][posn] = make_uint4(d[4], d[5], d[6], d[7]);
            }
        }
        __syncthreads();

        // ---- MFMA: 4 k-steps x 7 n-tiles ----
        #pragma unroll
        for (int kk = 0; kk < 4; ++kk) {
            bf16x8 bfr[7];
            #pragma unroll
            for (int n = 0; n < 7; ++n)
                bfr[n] = *reinterpret_cast<const bf16x8*>(&zxs[kk * 4 + g4][n * 16 + c16]);
            #pragma unroll
            for (int n = 0; n < 7; ++n)
                acc[n] = __builtin_amdgcn_mfma_f32_16x16x32_bf16(
                    afr[h * 4 + kk], bfr[n], acc[n], 0, 0, 0);
        }
        if (h == 0) __syncthreads();   // protect zxs before overwrite
    }

    // ---- epilogue: relu(acc + cst) -> out ----
    float* ob = out + (size_t)b * (COUT * T_DIM * J_DIM) + t0 * 25;
    #pragma unroll
    for (int r = 0; r < 4; ++r) {
        const int o = w * 16 + g4 * 4 + r;
        const float cv = cst[o];
        #pragma unroll
        for (int n = 0; n < 7; ++n) {
            const int pos = n * 16 + c16;
            if (pos < 100)
                ob[(size_t)o * 7500 + pos] = fmaxf(acc[n][r] + cv, 0.0f);
        }
    }
}

extern "C" void kernel_launch(void* const* d_in, const int* in_sizes, int n_in,
                              void* d_out, int out_size, void* d_ws, size_t ws_size,
                              hipStream_t stream)
{
    const float* x     = (const float*)d_in[0];
    const float* PA    = (const float*)d_in[1];
    const float* Wa    = (const float*)d_in[2];
    const float* ba    = (const float*)d_in[3];
    const float* Wb    = (const float*)d_in[4];
    const float* bb    = (const float*)d_in[5];
    const float* Wd    = (const float*)d_in[6];
    const float* bd    = (const float*)d_in[7];
    const float* Wdown = (const float*)d_in[8];
    const float* bdown = (const float*)d_in[9];
    const float* bn_g  = (const float*)d_in[10];
    const float* bn_b  = (const float*)d_in[11];
    const float* bn_m  = (const float*)d_in[12];
    const float* bn_v  = (const float*)d_in[13];
    const float* dn_g  = (const float*)d_in[14];
    const float* dn_b  = (const float*)d_in[15];
    const float* dn_m  = (const float*)d_in[16];
    const float* dn_v  = (const float*)d_in[17];

    float* ws   = (float*)d_ws;
    float* part = ws;                                   // 360,000 floats
    float* G    = ws + 360000;                          // 120,000 floats
    float* cst  = ws + 480000;                          // 128 floats
    unsigned short* Wpb = (unsigned short*)(ws + 480128);  // 32,768 bf16

    prep_kernel<<<1, 256, 0, stream>>>(Wd, bd, Wdown, bdown,
        bn_g, bn_b, bn_m, bn_v, dn_g, dn_b, dn_m, dn_v, Wpb, cst);
    scores_kernel<<<dim3(3 * SC_NSEG, B_DIM), 512, 0, stream>>>(x, Wa, ba, Wb, bb, part);
    softmax_kernel<<<dim3(B_DIM * 3), 64, 0, stream>>>(part, PA, G);
    main_kernel<<<dim3(T_DIM / 4, B_DIM), 512, 0, stream>>>(x, G, Wpb, cst, (float*)d_out);
}

// Round 5
// 452.025 us; speedup vs baseline: 5.1767x; 1.9884x over previous
//
#include <hip/hip_runtime.h>
#include <math.h>

#define T_DIM 300
#define J_DIM 25
#define CIN 64
#define COUT 128
#define B_DIM 64

typedef __attribute__((ext_vector_type(8))) short bf16x8;
typedef __attribute__((ext_vector_type(4))) float f32x4;

__device__ __forceinline__ unsigned short f2bf(float f) {
    union { float f; unsigned u; } v; v.f = f;
    unsigned r = v.u + 0x7FFF + ((v.u >> 16) & 1);   // RNE
    return (unsigned short)(r >> 16);
}

// ================= scores kernel: full MFMA =================
// grid (10 segs, 64 b), 256 threads. Each block: 30 t = 3 chunks of 10 t (250 pos).
#define SC_NSEG 10
#define SC_NCH  3

__global__ __launch_bounds__(256, 2) void scores_kernel(
    const float* __restrict__ x,
    const float* __restrict__ Wa, const float* __restrict__ ba,
    const float* __restrict__ Wb, const float* __restrict__ bb,
    float* __restrict__ part)
{
    __shared__ uint4 xsf[8][256];              // x B-fragments: [cgrp][pos], 8 ch packed bf16
    __shared__ unsigned short aT1[32][328];    // a1 transposed: [j][k*10+t]
    __shared__ unsigned short aT2[32][328];

    const int tid  = threadIdx.x;
    const int seg  = blockIdx.x;
    const int b    = blockIdx.y;
    const int lane = tid & 63;
    const int w    = tid >> 6;          // 0..3
    const int g4   = lane >> 4;
    const int c16  = lane & 15;
    const int jt1  = w >> 1, jt2 = w & 1;

    const float* xb = x + (size_t)b * (CIN * T_DIM * J_DIM);

    f32x4 gacc[3];
    #pragma unroll
    for (int i = 0; i < 3; ++i) gacc[i] = (f32x4){0.f, 0.f, 0.f, 0.f};

    for (int ch = 0; ch < SC_NCH; ++ch) {
        const int pb = seg * 750 + ch * 250;

        // ---- stage x chunk as packed bf16 fragments ----
        #pragma unroll
        for (int cg = 0; cg < 8; ++cg) {
            int p = pb + tid; if (p > 7499) p = 7499;   // clamp (pos>=250 unused)
            const float* xc = xb + (size_t)(cg * 8) * 7500 + p;
            unsigned d[4];
            #pragma unroll
            for (int m = 0; m < 4; ++m)
                d[m] = (unsigned)f2bf(xc[(2 * m) * 7500]) |
                       ((unsigned)f2bf(xc[(2 * m + 1) * 7500]) << 16);
            xsf[cg][tid] = make_uint4(d[0], d[1], d[2], d[3]);
        }
        __syncthreads();

        #pragma unroll
        for (int i = 0; i < 3; ++i) {
            // ---- embeddings via MFMA: pass 0 -> aT1 (Wa,ba), pass 1 -> aT2 (Wb,bb) ----
            #pragma unroll
            for (int pass = 0; pass < 2; ++pass) {
                const float* W  = pass ? Wb : Wa;
                const float* bs = pass ? bb : ba;
                bf16x8 afr[2][2];
                #pragma unroll
                for (int m = 0; m < 2; ++m)
                    #pragma unroll
                    for (int s = 0; s < 2; ++s) {
                        const float* wp = W + i * 2048 + (m * 16 + c16) * 64 + s * 32 + g4 * 8;
                        float4 f0 = *(const float4*)(wp);
                        float4 f1 = *(const float4*)(wp + 4);
                        bf16x8 t;
                        t[0] = f2bf(f0.x); t[1] = f2bf(f0.y); t[2] = f2bf(f0.z); t[3] = f2bf(f0.w);
                        t[4] = f2bf(f1.x); t[5] = f2bf(f1.y); t[6] = f2bf(f1.z); t[7] = f2bf(f1.w);
                        afr[m][s] = t;
                    }
                f32x4 acc[2][4];
                #pragma unroll
                for (int m = 0; m < 2; ++m) {
                    float4 bv = *(const float4*)(bs + i * 32 + m * 16 + g4 * 4);
                    #pragma unroll
                    for (int n = 0; n < 4; ++n)
                        acc[m][n] = (f32x4){bv.x, bv.y, bv.z, bv.w};
                }
                #pragma unroll
                for (int n = 0; n < 4; ++n) {
                    const int ptile = w * 4 + n;
                    #pragma unroll
                    for (int s = 0; s < 2; ++s) {
                        bf16x8 bfr = *reinterpret_cast<const bf16x8*>(&xsf[s * 4 + g4][ptile * 16 + c16]);
                        #pragma unroll
                        for (int m = 0; m < 2; ++m)
                            acc[m][n] = __builtin_amdgcn_mfma_f32_16x16x32_bf16(
                                afr[m][s], bfr, acc[m][n], 0, 0, 0);
                    }
                }
                unsigned short (*aT)[328] = pass ? aT2 : aT1;
                #pragma unroll
                for (int n = 0; n < 4; ++n) {
                    const int pos = (w * 4 + n) * 16 + c16;
                    if (pos < 250) {
                        const int t = pos / 25, j = pos - t * 25;
                        #pragma unroll
                        for (int m = 0; m < 2; ++m) {
                            const int k = m * 16 + g4 * 4;
                            aT[j][(k + 0) * 10 + t] = f2bf(acc[m][n][0]);
                            aT[j][(k + 1) * 10 + t] = f2bf(acc[m][n][1]);
                            aT[j][(k + 2) * 10 + t] = f2bf(acc[m][n][2]);
                            aT[j][(k + 3) * 10 + t] = f2bf(acc[m][n][3]);
                        }
                    }
                }
            }
            __syncthreads();

            // ---- gram: scores quadrant (jt1,jt2), K = 320 over (k,t) ----
            #pragma unroll
            for (int s = 0; s < 10; ++s) {
                bf16x8 af = *reinterpret_cast<const bf16x8*>(&aT1[jt1 * 16 + c16][s * 32 + g4 * 8]);
                bf16x8 bf = *reinterpret_cast<const bf16x8*>(&aT2[jt2 * 16 + c16][s * 32 + g4 * 8]);
                gacc[i] = __builtin_amdgcn_mfma_f32_16x16x32_bf16(af, bf, gacc[i], 0, 0, 0);
            }
            __syncthreads();
        }
    }

    // ---- write partial scores ----
    #pragma unroll
    for (int i = 0; i < 3; ++i) {
        const int j2 = jt2 * 16 + c16;
        #pragma unroll
        for (int r = 0; r < 4; ++r) {
            const int j1 = jt1 * 16 + g4 * 4 + r;
            if (j1 < 25 && j2 < 25)
                part[((size_t)(b * 3 + i) * SC_NSEG + seg) * 625 + j1 * 25 + j2] = gacc[i][r];
        }
    }
}

// ================= softmax =================
__global__ void softmax_kernel(const float* __restrict__ part,
                               const float* __restrict__ PA,
                               float* __restrict__ G)
{
    int bi = blockIdx.x;
    int b = bi / 3, i = bi - b * 3;
    int j2 = threadIdx.x;
    if (j2 >= 25) return;
    float v[25];
    float m = -1e30f;
    #pragma unroll
    for (int j1 = 0; j1 < 25; ++j1) {
        float s = 0.0f;
        for (int seg = 0; seg < SC_NSEG; ++seg)
            s += part[((size_t)bi * SC_NSEG + seg) * 625 + j1 * 25 + j2];
        v[j1] = s * (1.0f / 9600.0f);
        m = fmaxf(m, v[j1]);
    }
    float sum = 0.0f;
    #pragma unroll
    for (int j1 = 0; j1 < 25; ++j1) { v[j1] = expf(v[j1] - m); sum += v[j1]; }
    float r = 1.0f / sum;
    float* g = G + (size_t)bi * 625;
    #pragma unroll
    for (int j1 = 0; j1 < 25; ++j1)
        g[j1 * 25 + j2] = v[j1] * r + PA[(i * 25 + j1) * 25 + j2] + (j1 == j2 ? 1.0f : 0.0f);
}

// ================= prep: fold BN, emit W' bf16 [128][256] + cst =================
__global__ void prep_kernel(
    const float* __restrict__ Wd, const float* __restrict__ bd,
    const float* __restrict__ Wdown, const float* __restrict__ bdown,
    const float* __restrict__ g1, const float* __restrict__ b1,
    const float* __restrict__ m1, const float* __restrict__ v1,
    const float* __restrict__ g2, const float* __restrict__ b2,
    const float* __restrict__ m2, const float* __restrict__ v2,
    unsigned short* __restrict__ Wpb, float* __restrict__ cst)
{
    const int tid = threadIdx.x;
    for (int idx = tid; idx < COUT * 256; idx += 256) {
        int o = idx >> 8, k = idx & 255;
        float val;
        if (k < 192) {
            int i = k >> 6, c = k & 63;
            float inv = g1[o] * rsqrtf(v1[o] + 1e-5f);
            val = Wd[(i * COUT + o) * 64 + c] * inv;
        } else {
            float inv = g2[o] * rsqrtf(v2[o] + 1e-5f);
            val = Wdown[o * 64 + (k - 192)] * inv;
        }
        Wpb[idx] = f2bf(val);
    }
    if (tid < COUT) {
        int o = tid;
        float inv1 = g1[o] * rsqrtf(v1[o] + 1e-5f);
        float inv2 = g2[o] * rsqrtf(v2[o] + 1e-5f);
        cst[o] = (bd[o] + bd[COUT + o] + bd[2 * COUT + o]) * inv1
               + (b1[o] - m1[o] * inv1)
               + bdown[o] * inv2
               + (b2[o] - m2[o] * inv2);
    }
}

// ================= main fused kernel (exact R2 text — known good) =================
#define M_NCH 75     // chunks of 4 t

__global__ __launch_bounds__(512, 4) void main_kernel(
    const float* __restrict__ x, const float* __restrict__ G,
    const unsigned short* __restrict__ Wpb, const float* __restrict__ cst,
    float* __restrict__ out)
{
    __shared__ float xs[64][104];     // x window, fp32 (pos = t*25+j, 100 valid)
    __shared__ uint4 zxs[16][113];    // half-K B tile: [kgrp(8k)][pos] 16B units
    __shared__ float gl[1875];        // G for this b, fp32

    const int tid  = threadIdx.x;
    const int b    = blockIdx.y;
    const int t0   = blockIdx.x * 4;
    const int lane = tid & 63;
    const int w    = __builtin_amdgcn_readfirstlane(tid >> 6);  // wave 0..7
    const int g4   = lane >> 4;       // 0..3
    const int c16  = lane & 15;       // 0..15

    const float* xb = x + (size_t)b * (CIN * T_DIM * J_DIM) + t0 * 25;

    // A-fragments: wave w owns output rows [16w,16w+16); 8 k-steps of 32
    bf16x8 afr[8];
    {
        const unsigned short* wrow = Wpb + (w * 16 + c16) * 256 + g4 * 8;
        #pragma unroll
        for (int f = 0; f < 8; ++f)
            afr[f] = *reinterpret_cast<const bf16x8*>(wrow + f * 32);
    }

    // stage x window (64 rows x 100 floats, float4 loads)
    for (int idx = tid; idx < 64 * 25; idx += 512) {
        int c = idx / 25, q = idx - c * 25;
        *(float4*)&xs[c][q * 4] = *(const float4*)(xb + c * 7500 + q * 4);
    }
    // stage G
    for (int idx = tid; idx < 1875; idx += 512)
        gl[idx] = G[(size_t)b * 1875 + idx];

    // z-thread mapping
    const int pg   = tid >> 7;        // 0..3 -> c range [pg*16, pg*16+16)
    const int posn = tid & 127;       // valid if < 100
    const int tl   = posn / 25;
    const int jl   = posn - tl * 25;
    const bool zact = (posn < 100);

    f32x4 acc[7];
    #pragma unroll
    for (int n = 0; n < 7; ++n) acc[n] = (f32x4){0.f, 0.f, 0.f, 0.f};

    __syncthreads();

    for (int h = 0; h < 2; ++h) {
        // ---- produce zxs for this K-half (k = h*128 .. h*128+128) ----
        #pragma unroll
        for (int p = 0; p < 2; ++p) {
            const int slot = 2 * h + p;            // 0..2: z_i, 3: x
            if (zact) {
                float za[16];
                if (slot < 3) {
                    #pragma unroll
                    for (int i = 0; i < 16; ++i) za[i] = 0.0f;
                    const float* gcol = gl + slot * 625 + jl;
                    const int xo = tl * 25;
                    for (int jp = 0; jp < 25; ++jp) {
                        const float gv = gcol[jp * 25];
                        #pragma unroll
                        for (int i = 0; i < 16; ++i)
                            za[i] = fmaf(xs[pg * 16 + i][xo + jp], gv, za[i]);
                    }
                } else {
                    #pragma unroll
                    for (int i = 0; i < 16; ++i) za[i] = xs[pg * 16 + i][posn];
                }
                unsigned d[8];
                #pragma unroll
                for (int m = 0; m < 8; ++m)
                    d[m] = (unsigned)f2bf(za[2 * m]) | ((unsigned)f2bf(za[2 * m + 1]) << 16);
                const int kg = p * 8 + pg * 2;
                zxs[kg][posn]     = make_uint4(d[0], d[1], d[2], d[3]);
                zxs[kg + 1][posn] = make_uint4(d[4], d[5], d[6], d[7]);
            }
        }
        __syncthreads();

        // ---- MFMA: 4 k-steps x 7 n-tiles ----
        #pragma unroll
        for (int kk = 0; kk < 4; ++kk) {
            bf16x8 bfr[7];
            #pragma unroll
            for (int n = 0; n < 7; ++n)
                bfr[n] = *reinterpret_cast<const bf16x8*>(&zxs[kk * 4 + g4][n * 16 + c16]);
            #pragma unroll
            for (int n = 0; n < 7; ++n)
                acc[n] = __builtin_amdgcn_mfma_f32_16x16x32_bf16(
                    afr[h * 4 + kk], bfr[n], acc[n], 0, 0, 0);
        }
        if (h == 0) __syncthreads();   // protect zxs before overwrite
    }

    // ---- epilogue: relu(acc + cst) -> out ----
    float* ob = out + (size_t)b * (COUT * T_DIM * J_DIM) + t0 * 25;
    #pragma unroll
    for (int r = 0; r < 4; ++r) {
        const int o = w * 16 + g4 * 4 + r;
        const float cv = cst[o];
        #pragma unroll
        for (int n = 0; n < 7; ++n) {
            const int pos = n * 16 + c16;
            if (pos < 100)
                ob[(size_t)o * 7500 + pos] = fmaxf(acc[n][r] + cv, 0.0f);
        }
    }
}

extern "C" void kernel_launch(void* const* d_in, const int* in_sizes, int n_in,
                              void* d_out, int out_size, void* d_ws, size_t ws_size,
                              hipStream_t stream)
{
    const float* x     = (const float*)d_in[0];
    const float* PA    = (const float*)d_in[1];
    const float* Wa    = (const float*)d_in[2];
    const float* ba    = (const float*)d_in[3];
    const float* Wb    = (const float*)d_in[4];
    const float* bb    = (const float*)d_in[5];
    const float* Wd    = (const float*)d_in[6];
    const float* bd    = (const float*)d_in[7];
    const float* Wdown = (const float*)d_in[8];
    const float* bdown = (const float*)d_in[9];
    const float* bn_g  = (const float*)d_in[10];
    const float* bn_b  = (const float*)d_in[11];
    const float* bn_m  = (const float*)d_in[12];
    const float* bn_v  = (const float*)d_in[13];
    const float* dn_g  = (const float*)d_in[14];
    const float* dn_b  = (const float*)d_in[15];
    const float* dn_m  = (const float*)d_in[16];
    const float* dn_v  = (const float*)d_in[17];

    float* ws   = (float*)d_ws;
    float* part = ws;                                      // 64*3*10*625 = 1,200,000 f32
    float* G    = ws + 1200000;                            // 120,000 f32
    float* cst  = ws + 1320000;                            // 128 f32
    unsigned short* Wpb = (unsigned short*)(ws + 1320128); // 32,768 bf16

    prep_kernel<<<1, 256, 0, stream>>>(Wd, bd, Wdown, bdown,
        bn_g, bn_b, bn_m, bn_v, dn_g, dn_b, dn_m, dn_v, Wpb, cst);
    scores_kernel<<<dim3(SC_NSEG, B_DIM), 256, 0, stream>>>(x, Wa, ba, Wb, bb, part);
    softmax_kernel<<<dim3(B_DIM * 3), 64, 0, stream>>>(part, PA, G);
    main_kernel<<<dim3(M_NCH, B_DIM), 512, 0, stream>>>(x, G, Wpb, cst, (float*)d_out);
}

// Round 6
// 324.566 us; speedup vs baseline: 7.2096x; 1.3927x over previous
//
#include <hip/hip_runtime.h>
#include <math.h>

#define T_DIM 300
#define J_DIM 25
#define CIN 64
#define COUT 128
#define B_DIM 64

typedef __attribute__((ext_vector_type(8))) short bf16x8;
typedef __attribute__((ext_vector_type(4))) float f32x4;

__device__ __forceinline__ unsigned short f2bf(float f) {
    union { float f; unsigned u; } v; v.f = f;
    unsigned r = v.u + 0x7FFF + ((v.u >> 16) & 1);   // RNE
    return (unsigned short)(r >> 16);
}

__device__ __forceinline__ unsigned pkbf(float lo, float hi) {
    return (unsigned)f2bf(lo) | ((unsigned)f2bf(hi) << 16);
}

// ================= scores kernel: full MFMA (R4/R5 text, verified) =================
#define SC_NSEG 10
#define SC_NCH  3

__global__ __launch_bounds__(256, 2) void scores_kernel(
    const float* __restrict__ x,
    const float* __restrict__ Wa, const float* __restrict__ ba,
    const float* __restrict__ Wb, const float* __restrict__ bb,
    float* __restrict__ part)
{
    __shared__ uint4 xsf[8][256];              // x B-fragments: [cgrp][pos], 8 ch packed bf16
    __shared__ unsigned short aT1[32][328];    // a1 transposed: [j][k*10+t]
    __shared__ unsigned short aT2[32][328];

    const int tid  = threadIdx.x;
    const int seg  = blockIdx.x;
    const int b    = blockIdx.y;
    const int lane = tid & 63;
    const int w    = tid >> 6;          // 0..3
    const int g4   = lane >> 4;
    const int c16  = lane & 15;
    const int jt1  = w >> 1, jt2 = w & 1;

    const float* xb = x + (size_t)b * (CIN * T_DIM * J_DIM);

    f32x4 gacc[3];
    #pragma unroll
    for (int i = 0; i < 3; ++i) gacc[i] = (f32x4){0.f, 0.f, 0.f, 0.f};

    for (int ch = 0; ch < SC_NCH; ++ch) {
        const int pb = seg * 750 + ch * 250;

        #pragma unroll
        for (int cg = 0; cg < 8; ++cg) {
            int p = pb + tid; if (p > 7499) p = 7499;
            const float* xc = xb + (size_t)(cg * 8) * 7500 + p;
            unsigned d[4];
            #pragma unroll
            for (int m = 0; m < 4; ++m)
                d[m] = (unsigned)f2bf(xc[(2 * m) * 7500]) |
                       ((unsigned)f2bf(xc[(2 * m + 1) * 7500]) << 16);
            xsf[cg][tid] = make_uint4(d[0], d[1], d[2], d[3]);
        }
        __syncthreads();

        #pragma unroll
        for (int i = 0; i < 3; ++i) {
            #pragma unroll
            for (int pass = 0; pass < 2; ++pass) {
                const float* W  = pass ? Wb : Wa;
                const float* bs = pass ? bb : ba;
                bf16x8 afr[2][2];
                #pragma unroll
                for (int m = 0; m < 2; ++m)
                    #pragma unroll
                    for (int s = 0; s < 2; ++s) {
                        const float* wp = W + i * 2048 + (m * 16 + c16) * 64 + s * 32 + g4 * 8;
                        float4 f0 = *(const float4*)(wp);
                        float4 f1 = *(const float4*)(wp + 4);
                        bf16x8 t;
                        t[0] = f2bf(f0.x); t[1] = f2bf(f0.y); t[2] = f2bf(f0.z); t[3] = f2bf(f0.w);
                        t[4] = f2bf(f1.x); t[5] = f2bf(f1.y); t[6] = f2bf(f1.z); t[7] = f2bf(f1.w);
                        afr[m][s] = t;
                    }
                f32x4 acc[2][4];
                #pragma unroll
                for (int m = 0; m < 2; ++m) {
                    float4 bv = *(const float4*)(bs + i * 32 + m * 16 + g4 * 4);
                    #pragma unroll
                    for (int n = 0; n < 4; ++n)
                        acc[m][n] = (f32x4){bv.x, bv.y, bv.z, bv.w};
                }
                #pragma unroll
                for (int n = 0; n < 4; ++n) {
                    const int ptile = w * 4 + n;
                    #pragma unroll
                    for (int s = 0; s < 2; ++s) {
                        bf16x8 bfr = *reinterpret_cast<const bf16x8*>(&xsf[s * 4 + g4][ptile * 16 + c16]);
                        #pragma unroll
                        for (int m = 0; m < 2; ++m)
                            acc[m][n] = __builtin_amdgcn_mfma_f32_16x16x32_bf16(
                                afr[m][s], bfr, acc[m][n], 0, 0, 0);
                    }
                }
                unsigned short (*aT)[328] = pass ? aT2 : aT1;
                #pragma unroll
                for (int n = 0; n < 4; ++n) {
                    const int pos = (w * 4 + n) * 16 + c16;
                    if (pos < 250) {
                        const int t = pos / 25, j = pos - t * 25;
                        #pragma unroll
                        for (int m = 0; m < 2; ++m) {
                            const int k = m * 16 + g4 * 4;
                            aT[j][(k + 0) * 10 + t] = f2bf(acc[m][n][0]);
                            aT[j][(k + 1) * 10 + t] = f2bf(acc[m][n][1]);
                            aT[j][(k + 2) * 10 + t] = f2bf(acc[m][n][2]);
                            aT[j][(k + 3) * 10 + t] = f2bf(acc[m][n][3]);
                        }
                    }
                }
            }
            __syncthreads();

            #pragma unroll
            for (int s = 0; s < 10; ++s) {
                bf16x8 af = *reinterpret_cast<const bf16x8*>(&aT1[jt1 * 16 + c16][s * 32 + g4 * 8]);
                bf16x8 bf = *reinterpret_cast<const bf16x8*>(&aT2[jt2 * 16 + c16][s * 32 + g4 * 8]);
                gacc[i] = __builtin_amdgcn_mfma_f32_16x16x32_bf16(af, bf, gacc[i], 0, 0, 0);
            }
            __syncthreads();
        }
    }

    #pragma unroll
    for (int i = 0; i < 3; ++i) {
        const int j2 = jt2 * 16 + c16;
        #pragma unroll
        for (int r = 0; r < 4; ++r) {
            const int j1 = jt1 * 16 + g4 * 4 + r;
            if (j1 < 25 && j2 < 25)
                part[((size_t)(b * 3 + i) * SC_NSEG + seg) * 625 + j1 * 25 + j2] = gacc[i][r];
        }
    }
}

// ================= softmax (unchanged) =================
__global__ void softmax_kernel(const float* __restrict__ part,
                               const float* __restrict__ PA,
                               float* __restrict__ G)
{
    int bi = blockIdx.x;
    int b = bi / 3, i = bi - b * 3;
    int j2 = threadIdx.x;
    if (j2 >= 25) return;
    float v[25];
    float m = -1e30f;
    #pragma unroll
    for (int j1 = 0; j1 < 25; ++j1) {
        float s = 0.0f;
        for (int seg = 0; seg < SC_NSEG; ++seg)
            s += part[((size_t)bi * SC_NSEG + seg) * 625 + j1 * 25 + j2];
        v[j1] = s * (1.0f / 9600.0f);
        m = fmaxf(m, v[j1]);
    }
    float sum = 0.0f;
    #pragma unroll
    for (int j1 = 0; j1 < 25; ++j1) { v[j1] = expf(v[j1] - m); sum += v[j1]; }
    float r = 1.0f / sum;
    float* g = G + (size_t)bi * 625;
    #pragma unroll
    for (int j1 = 0; j1 < 25; ++j1)
        g[j1 * 25 + j2] = v[j1] * r + PA[(i * 25 + j1) * 25 + j2] + (j1 == j2 ? 1.0f : 0.0f);
}

// ================= prep (unchanged) =================
__global__ void prep_kernel(
    const float* __restrict__ Wd, const float* __restrict__ bd,
    const float* __restrict__ Wdown, const float* __restrict__ bdown,
    const float* __restrict__ g1, const float* __restrict__ b1,
    const float* __restrict__ m1, const float* __restrict__ v1,
    const float* __restrict__ g2, const float* __restrict__ b2,
    const float* __restrict__ m2, const float* __restrict__ v2,
    unsigned short* __restrict__ Wpb, float* __restrict__ cst)
{
    const int tid = threadIdx.x;
    for (int idx = tid; idx < COUT * 256; idx += 256) {
        int o = idx >> 8, k = idx & 255;
        float val;
        if (k < 192) {
            int i = k >> 6, c = k & 63;
            float inv = g1[o] * rsqrtf(v1[o] + 1e-5f);
            val = Wd[(i * COUT + o) * 64 + c] * inv;
        } else {
            float inv = g2[o] * rsqrtf(v2[o] + 1e-5f);
            val = Wdown[o * 64 + (k - 192)] * inv;
        }
        Wpb[idx] = f2bf(val);
    }
    if (tid < COUT) {
        int o = tid;
        float inv1 = g1[o] * rsqrtf(v1[o] + 1e-5f);
        float inv2 = g2[o] * rsqrtf(v2[o] + 1e-5f);
        cst[o] = (bd[o] + bd[COUT + o] + bd[2 * COUT + o]) * inv1
               + (b1[o] - m1[o] * inv1)
               + bdown[o] * inv2
               + (b2[o] - m2[o] * inv2);
    }
}

// ================= main fused kernel: transposed xs + single-pass z =================
#define M_NCH 75     // chunks of 4 t

__global__ __launch_bounds__(512, 4) void main_kernel(
    const float* __restrict__ x, const float* __restrict__ G,
    const unsigned short* __restrict__ Wpb, const float* __restrict__ cst,
    float* __restrict__ out)
{
    __shared__ float xs[100][68];     // TRANSPOSED x window: [pos][c], pad 68 (16B-aligned rows)
    __shared__ uint4 zxs[16][113];    // half-K B tile: [kgrp(8k)][pos] 16B units
    __shared__ float gl[1875];        // G for this b, fp32

    const int tid  = threadIdx.x;
    const int b    = blockIdx.y;
    const int t0   = blockIdx.x * 4;
    const int lane = tid & 63;
    const int w    = __builtin_amdgcn_readfirstlane(tid >> 6);  // wave 0..7
    const int g4   = lane >> 4;       // 0..3
    const int c16  = lane & 15;       // 0..15

    const float* xb = x + (size_t)b * (CIN * T_DIM * J_DIM) + t0 * 25;

    // stage x window transposed: xs[pos][c] = x[c][t0*25 + pos]
    for (int idx = tid; idx < 64 * 25; idx += 512) {
        int c = idx / 25, q = idx - c * 25;
        float4 v = *(const float4*)(xb + c * 7500 + q * 4);
        xs[q * 4 + 0][c] = v.x;
        xs[q * 4 + 1][c] = v.y;
        xs[q * 4 + 2][c] = v.z;
        xs[q * 4 + 3][c] = v.w;
    }
    // stage G
    for (int idx = tid; idx < 1875; idx += 512)
        gl[idx] = G[(size_t)b * 1875 + idx];

    // z-thread mapping (same as R5)
    const int pg   = tid >> 7;        // 0..3 -> c range [pg*16, pg*16+16)
    const int posn = tid & 127;       // valid if < 100
    const int tl   = posn / 25;
    const int jl   = posn - tl * 25;
    const bool zact = (posn < 100);
    const int xo   = tl * 25;

    f32x4 acc[7];
    #pragma unroll
    for (int n = 0; n < 7; ++n) acc[n] = (f32x4){0.f, 0.f, 0.f, 0.f};

    unsigned z2pk[8];                 // z2 carried in registers until h=1 fill

    __syncthreads();

    // ---- z-phase: all three subsets in ONE xs pass ----
    if (zact) {
        float za0[16], za1[16], za2[16];
        #pragma unroll
        for (int i = 0; i < 16; ++i) { za0[i] = 0.f; za1[i] = 0.f; za2[i] = 0.f; }
        for (int jp = 0; jp < 25; ++jp) {
            const float gv0 = gl[jp * 25 + jl];
            const float gv1 = gl[625 + jp * 25 + jl];
            const float gv2 = gl[1250 + jp * 25 + jl];
            const float* xr = &xs[xo + jp][pg * 16];
            float4 xa = *(const float4*)(xr);
            float4 xbv = *(const float4*)(xr + 4);
            float4 xc = *(const float4*)(xr + 8);
            float4 xd = *(const float4*)(xr + 12);
            float xv[16] = {xa.x, xa.y, xa.z, xa.w, xbv.x, xbv.y, xbv.z, xbv.w,
                            xc.x, xc.y, xc.z, xc.w, xd.x, xd.y, xd.z, xd.w};
            #pragma unroll
            for (int i = 0; i < 16; ++i) {
                za0[i] = fmaf(xv[i], gv0, za0[i]);
                za1[i] = fmaf(xv[i], gv1, za1[i]);
                za2[i] = fmaf(xv[i], gv2, za2[i]);
            }
        }
        // z0 -> kgrps 0..7, z1 -> kgrps 8..15 (exact R5 pair/kgrp mapping)
        unsigned d[8];
        #pragma unroll
        for (int m = 0; m < 8; ++m) d[m] = pkbf(za0[2 * m], za0[2 * m + 1]);
        zxs[pg * 2][posn]     = make_uint4(d[0], d[1], d[2], d[3]);
        zxs[pg * 2 + 1][posn] = make_uint4(d[4], d[5], d[6], d[7]);
        #pragma unroll
        for (int m = 0; m < 8; ++m) d[m] = pkbf(za1[2 * m], za1[2 * m + 1]);
        zxs[8 + pg * 2][posn]     = make_uint4(d[0], d[1], d[2], d[3]);
        zxs[8 + pg * 2 + 1][posn] = make_uint4(d[4], d[5], d[6], d[7]);
        #pragma unroll
        for (int m = 0; m < 8; ++m) z2pk[m] = pkbf(za2[2 * m], za2[2 * m + 1]);
    }
    __syncthreads();

    // ---- MFMA h=0 (k 0..127: z0,z1) ----
    {
        const unsigned short* wrow = Wpb + (w * 16 + c16) * 256 + g4 * 8;
        #pragma unroll
        for (int kk = 0; kk < 4; ++kk) {
            bf16x8 afr = *reinterpret_cast<const bf16x8*>(wrow + kk * 32);
            #pragma unroll
            for (int n = 0; n < 7; ++n) {
                bf16x8 bfr = *reinterpret_cast<const bf16x8*>(&zxs[kk * 4 + g4][n * 16 + c16]);
                acc[n] = __builtin_amdgcn_mfma_f32_16x16x32_bf16(afr, bfr, acc[n], 0, 0, 0);
            }
        }
    }
    __syncthreads();

    // ---- fill zxs for h=1: z2 (kgrps 0..7) + x copy (kgrps 8..15) ----
    if (zact) {
        zxs[pg * 2][posn]     = make_uint4(z2pk[0], z2pk[1], z2pk[2], z2pk[3]);
        zxs[pg * 2 + 1][posn] = make_uint4(z2pk[4], z2pk[5], z2pk[6], z2pk[7]);
        const float* xr = &xs[posn][pg * 16];
        float4 xa = *(const float4*)(xr);
        float4 xbv = *(const float4*)(xr + 4);
        float4 xc = *(const float4*)(xr + 8);
        float4 xd = *(const float4*)(xr + 12);
        unsigned d[8];
        d[0] = pkbf(xa.x, xa.y);  d[1] = pkbf(xa.z, xa.w);
        d[2] = pkbf(xbv.x, xbv.y); d[3] = pkbf(xbv.z, xbv.w);
        d[4] = pkbf(xc.x, xc.y);  d[5] = pkbf(xc.z, xc.w);
        d[6] = pkbf(xd.x, xd.y);  d[7] = pkbf(xd.z, xd.w);
        zxs[8 + pg * 2][posn]     = make_uint4(d[0], d[1], d[2], d[3]);
        zxs[8 + pg * 2 + 1][posn] = make_uint4(d[4], d[5], d[6], d[7]);
    }
    __syncthreads();

    // ---- MFMA h=1 (k 128..255: z2, x) ----
    {
        const unsigned short* wrow = Wpb + (w * 16 + c16) * 256 + 128 + g4 * 8;
        #pragma unroll
        for (int kk = 0; kk < 4; ++kk) {
            bf16x8 afr = *reinterpret_cast<const bf16x8*>(wrow + kk * 32);
            #pragma unroll
            for (int n = 0; n < 7; ++n) {
                bf16x8 bfr = *reinterpret_cast<const bf16x8*>(&zxs[kk * 4 + g4][n * 16 + c16]);
                acc[n] = __builtin_amdgcn_mfma_f32_16x16x32_bf16(afr, bfr, acc[n], 0, 0, 0);
            }
        }
    }

    // ---- epilogue: relu(acc + cst) -> out (R5 text) ----
    float* ob = out + (size_t)b * (COUT * T_DIM * J_DIM) + t0 * 25;
    #pragma unroll
    for (int r = 0; r < 4; ++r) {
        const int o = w * 16 + g4 * 4 + r;
        const float cv = cst[o];
        #pragma unroll
        for (int n = 0; n < 7; ++n) {
            const int pos = n * 16 + c16;
            if (pos < 100)
                ob[(size_t)o * 7500 + pos] = fmaxf(acc[n][r] + cv, 0.0f);
        }
    }
}

extern "C" void kernel_launch(void* const* d_in, const int* in_sizes, int n_in,
                              void* d_out, int out_size, void* d_ws, size_t ws_size,
                              hipStream_t stream)
{
    const float* x     = (const float*)d_in[0];
    const float* PA    = (const float*)d_in[1];
    const float* Wa    = (const float*)d_in[2];
    const float* ba    = (const float*)d_in[3];
    const float* Wb    = (const float*)d_in[4];
    const float* bb    = (const float*)d_in[5];
    const float* Wd    = (const float*)d_in[6];
    const float* bd    = (const float*)d_in[7];
    const float* Wdown = (const float*)d_in[8];
    const float* bdown = (const float*)d_in[9];
    const float* bn_g  = (const float*)d_in[10];
    const float* bn_b  = (const float*)d_in[11];
    const float* bn_m  = (const float*)d_in[12];
    const float* bn_v  = (const float*)d_in[13];
    const float* dn_g  = (const float*)d_in[14];
    const float* dn_b  = (const float*)d_in[15];
    const float* dn_m  = (const float*)d_in[16];
    const float* dn_v  = (const float*)d_in[17];

    float* ws   = (float*)d_ws;
    float* part = ws;                                      // 64*3*10*625 = 1,200,000 f32
    float* G    = ws + 1200000;                            // 120,000 f32
    float* cst  = ws + 1320000;                            // 128 f32
    unsigned short* Wpb = (unsigned short*)(ws + 1320128); // 32,768 bf16

    prep_kernel<<<1, 256, 0, stream>>>(Wd, bd, Wdown, bdown,
        bn_g, bn_b, bn_m, bn_v, dn_g, dn_b, dn_m, dn_v, Wpb, cst);
    scores_kernel<<<dim3(SC_NSEG, B_DIM), 256, 0, stream>>>(x, Wa, ba, Wb, bb, part);
    softmax_kernel<<<dim3(B_DIM * 3), 64, 0, stream>>>(part, PA, G);
    main_kernel<<<dim3(M_NCH, B_DIM), 512, 0, stream>>>(x, G, Wpb, cst, (float*)d_out);
}

// Round 7
// 276.404 us; speedup vs baseline: 8.4659x; 1.1742x over previous
//
#include <hip/hip_runtime.h>
#include <math.h>

#define T_DIM 300
#define J_DIM 25
#define CIN 64
#define COUT 128
#define B_DIM 64

typedef __attribute__((ext_vector_type(8))) short bf16x8;
typedef __attribute__((ext_vector_type(4))) float f32x4;

__device__ __forceinline__ unsigned short f2bf(float f) {
    union { float f; unsigned u; } v; v.f = f;
    unsigned r = v.u + 0x7FFF + ((v.u >> 16) & 1);   // RNE
    return (unsigned short)(r >> 16);
}

__device__ __forceinline__ unsigned pkbf(float lo, float hi) {
    return (unsigned)f2bf(lo) | ((unsigned)f2bf(hi) << 16);
}

// ================= scores kernel: full MFMA (R4/R5/R6 text, verified) =================
#define SC_NSEG 10
#define SC_NCH  3

__global__ __launch_bounds__(256, 2) void scores_kernel(
    const float* __restrict__ x,
    const float* __restrict__ Wa, const float* __restrict__ ba,
    const float* __restrict__ Wb, const float* __restrict__ bb,
    float* __restrict__ part)
{
    __shared__ uint4 xsf[8][256];              // x B-fragments: [cgrp][pos], 8 ch packed bf16
    __shared__ unsigned short aT1[32][328];    // a1 transposed: [j][k*10+t]
    __shared__ unsigned short aT2[32][328];

    const int tid  = threadIdx.x;
    const int seg  = blockIdx.x;
    const int b    = blockIdx.y;
    const int lane = tid & 63;
    const int w    = tid >> 6;          // 0..3
    const int g4   = lane >> 4;
    const int c16  = lane & 15;
    const int jt1  = w >> 1, jt2 = w & 1;

    const float* xb = x + (size_t)b * (CIN * T_DIM * J_DIM);

    f32x4 gacc[3];
    #pragma unroll
    for (int i = 0; i < 3; ++i) gacc[i] = (f32x4){0.f, 0.f, 0.f, 0.f};

    for (int ch = 0; ch < SC_NCH; ++ch) {
        const int pb = seg * 750 + ch * 250;

        #pragma unroll
        for (int cg = 0; cg < 8; ++cg) {
            int p = pb + tid; if (p > 7499) p = 7499;
            const float* xc = xb + (size_t)(cg * 8) * 7500 + p;
            unsigned d[4];
            #pragma unroll
            for (int m = 0; m < 4; ++m)
                d[m] = (unsigned)f2bf(xc[(2 * m) * 7500]) |
                       ((unsigned)f2bf(xc[(2 * m + 1) * 7500]) << 16);
            xsf[cg][tid] = make_uint4(d[0], d[1], d[2], d[3]);
        }
        __syncthreads();

        #pragma unroll
        for (int i = 0; i < 3; ++i) {
            #pragma unroll
            for (int pass = 0; pass < 2; ++pass) {
                const float* W  = pass ? Wb : Wa;
                const float* bs = pass ? bb : ba;
                bf16x8 afr[2][2];
                #pragma unroll
                for (int m = 0; m < 2; ++m)
                    #pragma unroll
                    for (int s = 0; s < 2; ++s) {
                        const float* wp = W + i * 2048 + (m * 16 + c16) * 64 + s * 32 + g4 * 8;
                        float4 f0 = *(const float4*)(wp);
                        float4 f1 = *(const float4*)(wp + 4);
                        bf16x8 t;
                        t[0] = f2bf(f0.x); t[1] = f2bf(f0.y); t[2] = f2bf(f0.z); t[3] = f2bf(f0.w);
                        t[4] = f2bf(f1.x); t[5] = f2bf(f1.y); t[6] = f2bf(f1.z); t[7] = f2bf(f1.w);
                        afr[m][s] = t;
                    }
                f32x4 acc[2][4];
                #pragma unroll
                for (int m = 0; m < 2; ++m) {
                    float4 bv = *(const float4*)(bs + i * 32 + m * 16 + g4 * 4);
                    #pragma unroll
                    for (int n = 0; n < 4; ++n)
                        acc[m][n] = (f32x4){bv.x, bv.y, bv.z, bv.w};
                }
                #pragma unroll
                for (int n = 0; n < 4; ++n) {
                    const int ptile = w * 4 + n;
                    #pragma unroll
                    for (int s = 0; s < 2; ++s) {
                        bf16x8 bfr = *reinterpret_cast<const bf16x8*>(&xsf[s * 4 + g4][ptile * 16 + c16]);
                        #pragma unroll
                        for (int m = 0; m < 2; ++m)
                            acc[m][n] = __builtin_amdgcn_mfma_f32_16x16x32_bf16(
                                afr[m][s], bfr, acc[m][n], 0, 0, 0);
                    }
                }
                unsigned short (*aT)[328] = pass ? aT2 : aT1;
                #pragma unroll
                for (int n = 0; n < 4; ++n) {
                    const int pos = (w * 4 + n) * 16 + c16;
                    if (pos < 250) {
                        const int t = pos / 25, j = pos - t * 25;
                        #pragma unroll
                        for (int m = 0; m < 2; ++m) {
                            const int k = m * 16 + g4 * 4;
                            aT[j][(k + 0) * 10 + t] = f2bf(acc[m][n][0]);
                            aT[j][(k + 1) * 10 + t] = f2bf(acc[m][n][1]);
                            aT[j][(k + 2) * 10 + t] = f2bf(acc[m][n][2]);
                            aT[j][(k + 3) * 10 + t] = f2bf(acc[m][n][3]);
                        }
                    }
                }
            }
            __syncthreads();

            #pragma unroll
            for (int s = 0; s < 10; ++s) {
                bf16x8 af = *reinterpret_cast<const bf16x8*>(&aT1[jt1 * 16 + c16][s * 32 + g4 * 8]);
                bf16x8 bf = *reinterpret_cast<const bf16x8*>(&aT2[jt2 * 16 + c16][s * 32 + g4 * 8]);
                gacc[i] = __builtin_amdgcn_mfma_f32_16x16x32_bf16(af, bf, gacc[i], 0, 0, 0);
            }
            __syncthreads();
        }
    }

    #pragma unroll
    for (int i = 0; i < 3; ++i) {
        const int j2 = jt2 * 16 + c16;
        #pragma unroll
        for (int r = 0; r < 4; ++r) {
            const int j1 = jt1 * 16 + g4 * 4 + r;
            if (j1 < 25 && j2 < 25)
                part[((size_t)(b * 3 + i) * SC_NSEG + seg) * 625 + j1 * 25 + j2] = gacc[i][r];
        }
    }
}

// ================= softmax: reduce partials, emit packed bf16 B-fragments Gb =================
// Gbg layout: [b*3+i][kg 0..3][33 cols] uint4; element (kg,col j) packs j' = kg*8..+7 (pairs)
__global__ void softmax_kernel(const float* __restrict__ part,
                               const float* __restrict__ PA,
                               uint4* __restrict__ Gbg)
{
    int bi = blockIdx.x;
    int b = bi / 3, i = bi - b * 3;
    int j2 = threadIdx.x;
    if (j2 >= 32) return;
    float gval[25];
    if (j2 < 25) {
        float v[25];
        float m = -1e30f;
        #pragma unroll
        for (int j1 = 0; j1 < 25; ++j1) {
            float s = 0.0f;
            for (int seg = 0; seg < SC_NSEG; ++seg)
                s += part[((size_t)bi * SC_NSEG + seg) * 625 + j1 * 25 + j2];
            v[j1] = s * (1.0f / 9600.0f);
            m = fmaxf(m, v[j1]);
        }
        float sum = 0.0f;
        #pragma unroll
        for (int j1 = 0; j1 < 25; ++j1) { v[j1] = expf(v[j1] - m); sum += v[j1]; }
        float r = 1.0f / sum;
        #pragma unroll
        for (int j1 = 0; j1 < 25; ++j1)
            gval[j1] = v[j1] * r + PA[(i * 25 + j1) * 25 + j2] + (j1 == j2 ? 1.0f : 0.0f);
    }
    #pragma unroll
    for (int kg = 0; kg < 4; ++kg) {
        unsigned d[4];
        #pragma unroll
        for (int mm = 0; mm < 4; ++mm) {
            int ja = kg * 8 + 2 * mm, jb2 = ja + 1;
            float va = (j2 < 25 && ja < 25) ? gval[ja] : 0.0f;
            float vb = (j2 < 25 && jb2 < 25) ? gval[jb2] : 0.0f;
            d[mm] = pkbf(va, vb);
        }
        Gbg[((size_t)bi * 4 + kg) * 33 + j2] = make_uint4(d[0], d[1], d[2], d[3]);
    }
}

// ================= prep: fold BN, emit W' bf16 [128][256], K-order [Wd0|Wdown|Wd1|Wd2] =================
__global__ void prep_kernel(
    const float* __restrict__ Wd, const float* __restrict__ bd,
    const float* __restrict__ Wdown, const float* __restrict__ bdown,
    const float* __restrict__ g1, const float* __restrict__ b1,
    const float* __restrict__ m1, const float* __restrict__ v1,
    const float* __restrict__ g2, const float* __restrict__ b2,
    const float* __restrict__ m2, const float* __restrict__ v2,
    unsigned short* __restrict__ Wpb, float* __restrict__ cst)
{
    const int tid = threadIdx.x;
    for (int idx = tid; idx < COUT * 256; idx += 256) {
        int o = idx >> 8, k = idx & 255;
        int region = k >> 6;           // 0:Wd0 1:Wdown 2:Wd1 3:Wd2
        float val;
        if (region == 1) {
            float inv = g2[o] * rsqrtf(v2[o] + 1e-5f);
            val = Wdown[o * 64 + (k & 63)] * inv;
        } else {
            int i = (region == 0) ? 0 : region - 1;
            float inv = g1[o] * rsqrtf(v1[o] + 1e-5f);
            val = Wd[(i * COUT + o) * 64 + (k & 63)] * inv;
        }
        Wpb[idx] = f2bf(val);
    }
    if (tid < COUT) {
        int o = tid;
        float inv1 = g1[o] * rsqrtf(v1[o] + 1e-5f);
        float inv2 = g2[o] * rsqrtf(v2[o] + 1e-5f);
        cst[o] = (bd[o] + bd[COUT + o] + bd[2 * COUT + o]) * inv1
               + (b1[o] - m1[o] * inv1)
               + bdown[o] * inv2
               + (b2[o] - m2[o] * inv2);
    }
}

// ================= main fused kernel: MFMA z-phase + MFMA GEMM =================
#define M_NCH 75     // chunks of 4 t

__global__ __launch_bounds__(512, 4) void main_kernel(
    const float* __restrict__ x, const uint4* __restrict__ Gbg,
    const unsigned short* __restrict__ Wpb, const float* __restrict__ cst,
    float* __restrict__ out)
{
    __shared__ unsigned short xs_bf[64][136];  // [c][t*32 + j'], j'>=25 zeroed, padded row
    __shared__ uint4 zxs[16][113];             // half-K B tile: [kgrp(8k)][pos]
    __shared__ uint4 gb[396];                  // [(i*4+kg)*33 + col]

    const int tid  = threadIdx.x;
    const int b    = blockIdx.y;
    const int t0   = blockIdx.x * 4;
    const int lane = tid & 63;
    const int w    = __builtin_amdgcn_readfirstlane(tid >> 6);  // wave 0..7
    const int g4   = lane >> 4;       // 0..3
    const int c16  = lane & 15;       // 0..15

    const float* xb = x + (size_t)b * (CIN * T_DIM * J_DIM) + t0 * 25;

    // ---- stage: xs_bf (bf16, zero-padded) + x copy into zxs kgrps 8..15 + Gb ----
    #pragma unroll
    for (int it = 0; it < 4; ++it) {
        const int u = tid + it * 512;          // (c, t, quad)
        const int quad = u & 7, t = (u >> 3) & 3, c = u >> 5;
        const int jp0 = quad * 4;
        float v[4];
        #pragma unroll
        for (int e = 0; e < 4; ++e) {
            const int jp = jp0 + e;
            v[e] = (jp < 25) ? xb[c * 7500 + t * 25 + jp] : 0.0f;
        }
        unsigned lo = pkbf(v[0], v[1]), hi = pkbf(v[2], v[3]);
        *reinterpret_cast<uint2*>(&xs_bf[c][t * 32 + jp0]) = make_uint2(lo, hi);
        const int kg = 8 + (c >> 3);
        const int sl = c & 7;
        #pragma unroll
        for (int e = 0; e < 4; ++e) {
            const int jp = jp0 + e;
            if (jp < 25)
                *((unsigned short*)&zxs[kg][t * 25 + jp] + sl) = f2bf(v[e]);
        }
    }
    if (tid < 396) gb[tid] = Gbg[(size_t)b * 396 + tid];

    f32x4 acc[7];
    #pragma unroll
    for (int n = 0; n < 7; ++n) acc[n] = (f32x4){0.f, 0.f, 0.f, 0.f};

    const int zt = w >> 1;            // wave's t row (0..3)
    const int mh = w & 1;             // wave's c-half

    __syncthreads();

    // z A-fragments (x_t rows), reused across all 3 subsets
    bf16x8 a_x[2];
    #pragma unroll
    for (int m = 0; m < 2; ++m)
        a_x[m] = *reinterpret_cast<const bf16x8*>(&xs_bf[(mh * 2 + m) * 16 + c16][zt * 32 + g4 * 8]);

    // z-pass for subset i -> zxs kgrp base kb
    auto zpass = [&](int i, int kb) {
        #pragma unroll
        for (int n = 0; n < 2; ++n) {
            bf16x8 bfr = *reinterpret_cast<const bf16x8*>(&gb[(i * 4 + g4) * 33 + n * 16 + c16]);
            #pragma unroll
            for (int m = 0; m < 2; ++m) {
                f32x4 d = __builtin_amdgcn_mfma_f32_16x16x32_bf16(
                    a_x[m], bfr, (f32x4){0.f, 0.f, 0.f, 0.f}, 0, 0, 0);
                const int j = n * 16 + c16;
                if (j < 25) {
                    const int cb = (mh * 2 + m) * 16 + g4 * 4;   // lane's 4 c-rows start
                    const int kg = kb + (cb >> 3);
                    const int hf = (cb >> 2) & 1;
                    unsigned lo = pkbf(d[0], d[1]), hi = pkbf(d[2], d[3]);
                    *reinterpret_cast<uint2*>(
                        reinterpret_cast<char*>(&zxs[kg][zt * 25 + j]) + hf * 8) = make_uint2(lo, hi);
                }
            }
        }
    };

    zpass(0, 0);                       // z0 -> kgrps 0..7 (x already in 8..15)
    __syncthreads();

    // ---- GEMM h0 (k 0..127 = [Wd0 | Wdown]) — R6 text ----
    {
        const unsigned short* wrow = Wpb + (w * 16 + c16) * 256 + g4 * 8;
        #pragma unroll
        for (int kk = 0; kk < 4; ++kk) {
            bf16x8 afr = *reinterpret_cast<const bf16x8*>(wrow + kk * 32);
            #pragma unroll
            for (int n = 0; n < 7; ++n) {
                bf16x8 bfr = *reinterpret_cast<const bf16x8*>(&zxs[kk * 4 + g4][n * 16 + c16]);
                acc[n] = __builtin_amdgcn_mfma_f32_16x16x32_bf16(afr, bfr, acc[n], 0, 0, 0);
            }
        }
    }
    __syncthreads();

    zpass(1, 0);                       // z1 -> kgrps 0..7
    zpass(2, 8);                       // z2 -> kgrps 8..15
    __syncthreads();

    // ---- GEMM h1 (k 128..255 = [Wd1 | Wd2]) — R6 text ----
    {
        const unsigned short* wrow = Wpb + (w * 16 + c16) * 256 + 128 + g4 * 8;
        #pragma unroll
        for (int kk = 0; kk < 4; ++kk) {
            bf16x8 afr = *reinterpret_cast<const bf16x8*>(wrow + kk * 32);
            #pragma unroll
            for (int n = 0; n < 7; ++n) {
                bf16x8 bfr = *reinterpret_cast<const bf16x8*>(&zxs[kk * 4 + g4][n * 16 + c16]);
                acc[n] = __builtin_amdgcn_mfma_f32_16x16x32_bf16(afr, bfr, acc[n], 0, 0, 0);
            }
        }
    }

    // ---- epilogue: relu(acc + cst) -> out (R6 text) ----
    float* ob = out + (size_t)b * (COUT * T_DIM * J_DIM) + t0 * 25;
    #pragma unroll
    for (int r = 0; r < 4; ++r) {
        const int o = w * 16 + g4 * 4 + r;
        const float cv = cst[o];
        #pragma unroll
        for (int n = 0; n < 7; ++n) {
            const int pos = n * 16 + c16;
            if (pos < 100)
                ob[(size_t)o * 7500 + pos] = fmaxf(acc[n][r] + cv, 0.0f);
        }
    }
}

extern "C" void kernel_launch(void* const* d_in, const int* in_sizes, int n_in,
                              void* d_out, int out_size, void* d_ws, size_t ws_size,
                              hipStream_t stream)
{
    const float* x     = (const float*)d_in[0];
    const float* PA    = (const float*)d_in[1];
    const float* Wa    = (const float*)d_in[2];
    const float* ba    = (const float*)d_in[3];
    const float* Wb    = (const float*)d_in[4];
    const float* bb    = (const float*)d_in[5];
    const float* Wd    = (const float*)d_in[6];
    const float* bd    = (const float*)d_in[7];
    const float* Wdown = (const float*)d_in[8];
    const float* bdown = (const float*)d_in[9];
    const float* bn_g  = (const float*)d_in[10];
    const float* bn_b  = (const float*)d_in[11];
    const float* bn_m  = (const float*)d_in[12];
    const float* bn_v  = (const float*)d_in[13];
    const float* dn_g  = (const float*)d_in[14];
    const float* dn_b  = (const float*)d_in[15];
    const float* dn_m  = (const float*)d_in[16];
    const float* dn_v  = (const float*)d_in[17];

    float* ws   = (float*)d_ws;
    float* part = ws;                                      // 1,200,000 f32
    uint4* Gbg  = (uint4*)(ws + 1200000);                  // 64*396 uint4 = 101,376 f32-equiv
    float* cst  = ws + 1301376;                            // 128 f32
    unsigned short* Wpb = (unsigned short*)(ws + 1301504); // 32,768 bf16

    prep_kernel<<<1, 256, 0, stream>>>(Wd, bd, Wdown, bdown,
        bn_g, bn_b, bn_m, bn_v, dn_g, dn_b, dn_m, dn_v, Wpb, cst);
    scores_kernel<<<dim3(SC_NSEG, B_DIM), 256, 0, stream>>>(x, Wa, ba, Wb, bb, part);
    softmax_kernel<<<dim3(B_DIM * 3), 64, 0, stream>>>(part, PA, Gbg);
    main_kernel<<<dim3(M_NCH, B_DIM), 512, 0, stream>>>(x, Gbg, Wpb, cst, (float*)d_out);
}